// Round 5
// baseline (199.663 us; speedup 1.0000x reference)
//
#include <hip/hip_runtime.h>
#include <hip/hip_bf16.h>
#include <cstddef>
#include <cstdint>

// GINConvFFT round 5: single k-summed diffusion GEMM (K=2048) + fused BN partials.
//   prep:  xb = bf16(x); MallC[n][2s*512+m] = (1+eps)I+A_s; MT; Wt[k][o][d]
//   msq:   MallC[n][(2s+1)*512+m] = (M_s^2)[n][m]           (MFMA)
//   zgemm: Zcat[b][o][k*512+m] = sum_d Wt[k][o][d]*xb[b*512+m][d]   (MFMA, 512 blk)
//   ysum:  Ysum[b][n][o] = sum_{k,m} MallC[n][k*512+m]*Zcat[b][o][k*512+m]
//          + per-block BN partials                           (MFMA, 512 blk)
//   bn_final, bn_out (BN+ReLU+w2+b2).
#define B_   32
#define N_   512
#define D_   768
#define OUT_ 64
#define R_   (B_ * N_)

typedef unsigned short u16;
typedef __bf16 bf16x8 __attribute__((ext_vector_type(8)));
typedef float  f32x4  __attribute__((ext_vector_type(4)));
typedef unsigned short u16x8 __attribute__((ext_vector_type(8)));

__device__ __forceinline__ u16 f2bf(float f) {
    __hip_bfloat16 h = __float2bfloat16(f);
    return __builtin_bit_cast(u16, h);
}

__device__ __forceinline__ f32x4 mfma16(u16x8 a, u16x8 b, f32x4 c) {
    return __builtin_amdgcn_mfma_f32_16x16x32_bf16(
        __builtin_bit_cast(bf16x8, a), __builtin_bit_cast(bf16x8, b), c, 0, 0, 0);
}

// async global->LDS, 16B/lane; LDS dest = wave-uniform base + lane*16
__device__ __forceinline__ void gl2lds16(const void* g, void* l) {
    __builtin_amdgcn_global_load_lds(
        (const __attribute__((address_space(1))) unsigned int*)g,
        (__attribute__((address_space(3))) unsigned int*)l, 16, 0, 0);
}

// ---------------------------------------------------------------------------
// prep: [0,6144) cast x->bf16 | [6144,6656) build M,MT | [6656,7424) build Wt
// ---------------------------------------------------------------------------
__global__ __launch_bounds__(256) void prep(
    const float* __restrict__ x, const float* __restrict__ support,
    const float* __restrict__ weight, const float* __restrict__ epsp,
    u16* __restrict__ xb, u16* __restrict__ MallC, u16* __restrict__ MT,
    u16* __restrict__ Wt)
{
    const int blk = blockIdx.x, tid = threadIdx.x;
    __shared__ float t[32][33];
    if (blk < 6144) {
        int i = (blk * 256 + tid) * 8;
        f32x4 a = *(const f32x4*)(x + i);
        f32x4 b = *(const f32x4*)(x + i + 4);
        u16x8 o;
#pragma unroll
        for (int j = 0; j < 4; ++j) { o[j] = f2bf(a[j]); o[4 + j] = f2bf(b[j]); }
        *(u16x8*)(xb + i) = o;
    } else if (blk < 6656) {
        int local = blk - 6144;
        int s = local >> 8, rem = local & 255;
        int n0 = (rem >> 4) * 32, m0 = (rem & 15) * 32;
        const float f = 1.0f + epsp[0];
        const float* S = support + (size_t)s * 262144;
#pragma unroll
        for (int p = 0; p < 4; ++p) {
            int nl = p * 8 + (tid >> 5), ml = tid & 31;
            float v = S[(size_t)(n0 + nl) * 512 + m0 + ml];
            if (n0 + nl == m0 + ml) v += f;
            MallC[(size_t)(n0 + nl) * 2048 + s * 1024 + m0 + ml] = f2bf(v);
            t[nl][ml] = v;
        }
        __syncthreads();
#pragma unroll
        for (int p = 0; p < 4; ++p) {
            int ml = p * 8 + (tid >> 5), nl = tid & 31;
            MT[(size_t)s * 262144 + (size_t)(m0 + ml) * 512 + n0 + nl] = f2bf(t[nl][ml]);
        }
    } else {
        int idx = (blk - 6656) * 256 + tid;         // 4*64*768
        int k = idx / 49152, rem = idx % 49152;
        int o = rem / 768, d = rem % 768;
        int l = d >> 6, hh = d & 63;
        Wt[idx] = f2bf(weight[((size_t)l * 256 + hh * 4 + k) * 64 + o]);
    }
}

// ---------------------------------------------------------------------------
// msq: C[n][m'] = sum_m M_s[n][m]*MT_s[m'][m] -> MallC col slice (2s+1).
// 128x128 tile, K=512. grid (4,4,2), block 256 (2x2 waves of 64x64).
// ---------------------------------------------------------------------------
__global__ __launch_bounds__(256) void msq(
    const u16* __restrict__ MallC_in, const u16* __restrict__ MT,
    u16* __restrict__ MallC_out)
{
    __shared__ __align__(16) u16 sm[8192];
    u16* Ps = sm; u16* Qs = sm + 4096;
    const int tid = threadIdx.x, lane = tid & 63, wid = tid >> 6;
    const int wr = wid >> 1, wc = wid & 1;
    const int s = blockIdx.z, i0 = blockIdx.y * 128, j0 = blockIdx.x * 128;
    const int lrow = lane & 15, lk = (lane >> 4) * 8;

    const u16* gsrc[4]; u16* ldst[4];
#pragma unroll
    for (int t = 0; t < 4; ++t) {
        int idx = wid * 4 + t;
        if (idx < 8) { gsrc[t] = MallC_in + (size_t)(i0 + idx * 16 + lrow) * 2048 + s * 1024 + lk; ldst[t] = Ps + idx * 512; }
        else { int s2 = idx - 8; gsrc[t] = MT + (size_t)s * 262144 + (size_t)(j0 + s2 * 16 + lrow) * 512 + lk; ldst[t] = Qs + s2 * 512; }
    }
    f32x4 acc[4][4] = {};
    for (int k0 = 0; k0 < 512; k0 += 32) {
#pragma unroll
        for (int t = 0; t < 4; ++t) gl2lds16(gsrc[t], ldst[t]);
#pragma unroll
        for (int t = 0; t < 4; ++t) gsrc[t] += 32;
        __syncthreads();
        u16x8 af[4], bq[4];
#pragma unroll
        for (int f = 0; f < 4; ++f) af[f] = *(const u16x8*)(Ps + (wr * 4 + f) * 512 + lane * 8);
#pragma unroll
        for (int f = 0; f < 4; ++f) bq[f] = *(const u16x8*)(Qs + (wc * 4 + f) * 512 + lane * 8);
#pragma unroll
        for (int fi = 0; fi < 4; ++fi)
#pragma unroll
            for (int fj = 0; fj < 4; ++fj) acc[fi][fj] = mfma16(af[fi], bq[fj], acc[fi][fj]);
        __syncthreads();
    }
    const int q = lane >> 4;
#pragma unroll
    for (int fi = 0; fi < 4; ++fi)
#pragma unroll
        for (int fj = 0; fj < 4; ++fj)
#pragma unroll
            for (int r = 0; r < 4; ++r) {
                int n = i0 + wr * 64 + fi * 16 + q * 4 + r;
                int c = j0 + wc * 64 + fj * 16 + lrow;
                MallC_out[(size_t)n * 2048 + (2 * s + 1) * 512 + c] = f2bf(acc[fi][fj][r]);
            }
}

// ---------------------------------------------------------------------------
// zgemm: Zcat[(b*64+o)*2048 + k*512 + m] = sum_d Wt[k*64+o][d] * xb[b*512+m][d]
// block tile 64i x 128j, K=768. grid (128 j-tiles, 4 k), block 256.
// waves 2x2: wr over i (32), wc over j (64). 2048 waves -> 2/SIMD.
// ---------------------------------------------------------------------------
__global__ __launch_bounds__(256) void zgemm(
    const u16* __restrict__ Wt, const u16* __restrict__ xb, u16* __restrict__ Z)
{
    __shared__ __align__(16) u16 sm[9216];   // staging 12x512 | repack 4x(32x72)
    u16* As = sm; u16* Bs = sm + 2048;
    const int tid = threadIdx.x, lane = tid & 63, wid = tid >> 6;
    const int wr = wid >> 1, wc = wid & 1;
    const int j0 = blockIdx.x * 128, k = blockIdx.y;
    const int b = j0 >> 9, m0 = j0 & 511;
    const int lrow = lane & 15, lk = (lane >> 4) * 8;

    const u16* gsrc[3]; u16* ldst[3];
#pragma unroll
    for (int t = 0; t < 3; ++t) {
        int idx = wid * 3 + t;
        if (idx < 4) { gsrc[t] = Wt + (size_t)(k * 64 + idx * 16 + lrow) * 768 + lk; ldst[t] = As + idx * 512; }
        else { int s2 = idx - 4; gsrc[t] = xb + (size_t)(j0 + s2 * 16 + lrow) * 768 + lk; ldst[t] = Bs + s2 * 512; }
    }
    f32x4 acc[2][4] = {};
    for (int k0 = 0; k0 < 768; k0 += 32) {
#pragma unroll
        for (int t = 0; t < 3; ++t) gl2lds16(gsrc[t], ldst[t]);
#pragma unroll
        for (int t = 0; t < 3; ++t) gsrc[t] += 32;
        __syncthreads();
        u16x8 af[2], bq[4];
#pragma unroll
        for (int f = 0; f < 2; ++f) af[f] = *(const u16x8*)(As + (wr * 2 + f) * 512 + lane * 8);
#pragma unroll
        for (int f = 0; f < 4; ++f) bq[f] = *(const u16x8*)(Bs + (wc * 4 + f) * 512 + lane * 8);
#pragma unroll
        for (int fi = 0; fi < 2; ++fi)
#pragma unroll
            for (int fj = 0; fj < 4; ++fj) acc[fi][fj] = mfma16(af[fi], bq[fj], acc[fi][fj]);
        __syncthreads();
    }
    // repack per wave: 32 o-rows x 64 m (stride 72 u16)
    u16* Rw = sm + wid * 2304;
    const int q = lane >> 4;
#pragma unroll
    for (int fi = 0; fi < 2; ++fi)
#pragma unroll
        for (int fj = 0; fj < 4; ++fj)
#pragma unroll
            for (int r = 0; r < 4; ++r)
                Rw[(fi * 16 + q * 4 + r) * 72 + fj * 16 + lrow] = f2bf(acc[fi][fj][r]);
    __syncthreads();
#pragma unroll
    for (int p = 0; p < 4; ++p) {
        int row = p * 8 + (lane >> 3);           // o within wave half
        int cc = (lane & 7) * 8;                 // m within 64
        int o = wr * 32 + row;
        u16x8 v = *(const u16x8*)(Rw + row * 72 + cc);
        *(u16x8*)(Z + ((size_t)(b * 64 + o) * 4 + k) * 512 + m0 + wc * 64 + cc) = v;
    }
}

// ---------------------------------------------------------------------------
// ysum: Ysum[b][n][o] = sum_{k,m} MallC[n][k*512+m] * Zcat[(b*64+o)][k*512+m]
// grid (16 n-tiles of 32, 32 b), block 256; wave w handles k=w (K=512 each),
// then LDS k-reduce + Ysum write + BN partials. 2048 waves -> 2/SIMD.
// ---------------------------------------------------------------------------
__global__ __launch_bounds__(256) void ysum(
    const u16* __restrict__ MallC, const u16* __restrict__ Z,
    float* __restrict__ Ysum, float* __restrict__ part)
{
    __shared__ __align__(16) char smem[43520];
    u16*   St = (u16*)smem;              // staging: wave base wid*6*512 u16
    float* Rk = (float*)smem;            // [4][32][68] f32 (overlays staging)
    float* vs = (float*)(smem + 34816);  // [32][68]
    const int tid = threadIdx.x, lane = tid & 63, wid = tid >> 6;
    const int n0 = blockIdx.x * 32, b = blockIdx.y;
    const int lrow = lane & 15, lk = (lane >> 4) * 8;

    const u16* gsrc[6]; u16* ldst[6];
#pragma unroll
    for (int t = 0; t < 2; ++t) {        // A: 32 n-rows
        gsrc[t] = MallC + (size_t)(n0 + t * 16 + lrow) * 2048 + wid * 512 + lk;
        ldst[t] = St + (wid * 6 + t) * 512;
    }
#pragma unroll
    for (int t = 0; t < 4; ++t) {        // B: 64 o-rows
        gsrc[2 + t] = Z + (size_t)(b * 64 + t * 16 + lrow) * 2048 + wid * 512 + lk;
        ldst[2 + t] = St + (wid * 6 + 2 + t) * 512;
    }
    f32x4 acc[2][4] = {};
    for (int k0 = 0; k0 < 512; k0 += 32) {
#pragma unroll
        for (int t = 0; t < 6; ++t) gl2lds16(gsrc[t], ldst[t]);
#pragma unroll
        for (int t = 0; t < 6; ++t) gsrc[t] += 32;
        __syncthreads();
        u16x8 af[2], bq[4];
#pragma unroll
        for (int f = 0; f < 2; ++f) af[f] = *(const u16x8*)(St + (wid * 6 + f) * 512 + lane * 8);
#pragma unroll
        for (int f = 0; f < 4; ++f) bq[f] = *(const u16x8*)(St + (wid * 6 + 2 + f) * 512 + lane * 8);
#pragma unroll
        for (int fi = 0; fi < 2; ++fi)
#pragma unroll
            for (int fj = 0; fj < 4; ++fj) acc[fi][fj] = mfma16(af[fi], bq[fj], acc[fi][fj]);
        __syncthreads();
    }
    // per-k partial tiles -> LDS
    const int q = lane >> 4;
#pragma unroll
    for (int fi = 0; fi < 2; ++fi)
#pragma unroll
        for (int fj = 0; fj < 4; ++fj)
#pragma unroll
            for (int r = 0; r < 4; ++r)
                Rk[wid * 2176 + (fi * 16 + q * 4 + r) * 68 + fj * 16 + lrow] = acc[fi][fj][r];
    __syncthreads();
    // k-sum, write Ysum, stage for BN partials
    {
        const int r = tid >> 3, c0 = (tid & 7) * 8;
        float v[8];
#pragma unroll
        for (int j = 0; j < 8; ++j) {
            v[j] = Rk[r * 68 + c0 + j] + Rk[2176 + r * 68 + c0 + j]
                 + Rk[4352 + r * 68 + c0 + j] + Rk[6528 + r * 68 + c0 + j];
            vs[r * 68 + c0 + j] = v[j];
        }
        float* dst = Ysum + ((size_t)(b * 512 + n0 + r)) * 64 + c0;
        f32x4 v0, v1;
#pragma unroll
        for (int j = 0; j < 4; ++j) { v0[j] = v[j]; v1[j] = v[4 + j]; }
        *(f32x4*)dst = v0;
        *(f32x4*)(dst + 4) = v1;
    }
    __syncthreads();
    if (tid < 64) {
        float s = 0.f, s2 = 0.f;
#pragma unroll
        for (int r2 = 0; r2 < 32; ++r2) {
            float u = vs[r2 * 68 + tid];
            s += u; s2 += u * u;
        }
        int blk = blockIdx.y * 16 + blockIdx.x;
        part[blk * 128 + tid]      = s;
        part[blk * 128 + 64 + tid] = s2;
    }
}

// ---------------------------------------------------------------------------
__global__ __launch_bounds__(256) void bn_final(
    const float* __restrict__ part, float* __restrict__ stats)
{
    const int tid = threadIdx.x;
    const int c = tid & 63, g = tid >> 6;
    float s = 0.f, s2 = 0.f;
    for (int b = g; b < 512; b += 4) {
        s  += part[b * 128 + c];
        s2 += part[b * 128 + 64 + c];
    }
    __shared__ float ls[4][64], ls2[4][64];
    ls[g][c] = s; ls2[g][c] = s2;
    __syncthreads();
    if (tid < 64) {
        float t = 0.f, t2 = 0.f;
#pragma unroll
        for (int g2 = 0; g2 < 4; ++g2) { t += ls[g2][tid]; t2 += ls2[g2][tid]; }
        float mean = t * (1.0f / R_);
        float var  = t2 * (1.0f / R_) - mean * mean;
        stats[tid]      = mean;
        stats[64 + tid] = rsqrtf(var + 1e-5f);
    }
}

// ---------------------------------------------------------------------------
// bn_out: out[r][o] = sum_c relu(bn(Ysum[r][c])) * w2[o][c] + b2[o]. grid 256.
// ---------------------------------------------------------------------------
__global__ __launch_bounds__(256) void bn_out(
    const float* __restrict__ Ysum, const float* __restrict__ stats,
    const float* __restrict__ gamma, const float* __restrict__ beta,
    const float* __restrict__ w2, const float* __restrict__ b2,
    float* __restrict__ out)
{
    __shared__ float ys[64 * 68];
    __shared__ float w2s[64 * 65];
    __shared__ float mn[64], rs[64], ga[64], be[64], bb[64];
    const int tid = threadIdx.x;
    const int r0 = blockIdx.x * 64;
#pragma unroll
    for (int i = 0; i < 16; ++i) {
        int idx = tid + i * 256;
        w2s[(idx >> 6) * 65 + (idx & 63)] = w2[idx];
    }
    if (tid < 64) {
        mn[tid] = stats[tid]; rs[tid] = stats[64 + tid];
        ga[tid] = gamma[tid]; be[tid] = beta[tid]; bb[tid] = b2[tid];
    }
    __syncthreads();
    const int o = tid & 63, rg = tid >> 6;
#pragma unroll
    for (int p = 0; p < 16; ++p) {
        int rl = p * 4 + rg;
        float v = Ysum[(size_t)(r0 + rl) * 64 + o];
        v = (v - mn[o]) * rs[o] * ga[o] + be[o];
        ys[o * 68 + rl] = fmaxf(v, 0.f);
    }
    __syncthreads();
    float acc[16];
#pragma unroll
    for (int j = 0; j < 16; ++j) acc[j] = bb[o];
    for (int c = 0; c < 64; ++c) {
        float wv = w2s[o * 65 + c];
        const float* yr = ys + c * 68 + rg * 16;
        f32x4 y0 = *(const f32x4*)(yr);
        f32x4 y1 = *(const f32x4*)(yr + 4);
        f32x4 y2 = *(const f32x4*)(yr + 8);
        f32x4 y3 = *(const f32x4*)(yr + 12);
#pragma unroll
        for (int j = 0; j < 4; ++j) {
            acc[j]      = fmaf(wv, y0[j], acc[j]);
            acc[4 + j]  = fmaf(wv, y1[j], acc[4 + j]);
            acc[8 + j]  = fmaf(wv, y2[j], acc[8 + j]);
            acc[12 + j] = fmaf(wv, y3[j], acc[12 + j]);
        }
    }
#pragma unroll
    for (int j = 0; j < 16; ++j)
        out[(size_t)(r0 + rg * 16 + j) * OUT_ + o] = acc[j];
}

// ---------------------------------------------------------------------------
extern "C" void kernel_launch(void* const* d_in, const int* in_sizes, int n_in,
                              void* d_out, int out_size, void* d_ws, size_t ws_size,
                              hipStream_t stream)
{
    const float* x       = (const float*)d_in[0];
    const float* support = (const float*)d_in[1];
    const float* weight  = (const float*)d_in[2];
    const float* eps     = (const float*)d_in[3];
    const float* gamma   = (const float*)d_in[4];
    const float* beta    = (const float*)d_in[5];
    const float* w2      = (const float*)d_in[6];
    const float* b2      = (const float*)d_in[7];
    float* out = (float*)d_out;

    char* ws = (char*)d_ws;
    u16*   xb    = (u16*)(ws);                      // 25,165,824
    u16*   MallC = (u16*)(ws + 25165824);           //  2,097,152  [512][2048]
    u16*   MT    = (u16*)(ws + 27262976);           //  1,048,576
    u16*   Wt    = (u16*)(ws + 28311552);           //    393,216
    u16*   Z     = (u16*)(ws + 28704768);           //  8,388,608  [2048][2048]
    float* Ysum  = (float*)(ws + 37093376);         //  4,194,304
    float* part  = (float*)(ws + 41287680);         //    262,144
    float* stats = (float*)(ws + 41549824);         //        512

    prep    <<<7424,            256, 0, stream>>>(x, support, weight, eps, xb, MallC, MT, Wt);
    msq     <<<dim3(4, 4, 2),   256, 0, stream>>>(MallC, MT, MallC);
    zgemm   <<<dim3(128, 4),    256, 0, stream>>>(Wt, xb, Z);
    ysum    <<<dim3(16, 32),    256, 0, stream>>>(MallC, Z, Ysum, part);
    bn_final<<<1,               256, 0, stream>>>(part, stats);
    bn_out  <<<256,             256, 0, stream>>>(Ysum, stats, gamma, beta, w2, b2, out);
}